// Round 2
// baseline (6456.513 us; speedup 1.0000x reference)
//
#include <hip/hip_runtime.h>
#include <math.h>
#include <cstdint>

// ---------------- problem constants ----------------
#define NN     131072     // nodes
#define DDIM   128        // hidden dim
#define NHEAD  4
#define HDIM   32
#define NTYPE  3
#define NEDGE  262144     // edges per type (2^18)
#define NGRAPH 512
#define EPSV   1e-6f
#define SLOPEV 0.2f

// ---------------- helpers ----------------
__device__ __forceinline__ float lrelu(float x){ return x >= 0.f ? x : SLOPEV*x; }
__device__ __forceinline__ float gelu_f(float x){ return 0.5f*x*(1.f+erff(x*0.70710678118654752f)); }
__device__ __forceinline__ void atomicMaxF(float* a, float v){
  if (v >= 0.f) atomicMax((int*)a, __float_as_int(v));
  else          atomicMin((unsigned int*)a, __float_as_uint(v));
}
__device__ __forceinline__ void load8(const float* p, float* o){
  float4 a = *reinterpret_cast<const float4*>(p);
  float4 b = *reinterpret_cast<const float4*>(p+4);
  o[0]=a.x;o[1]=a.y;o[2]=a.z;o[3]=a.w;o[4]=b.x;o[5]=b.y;o[6]=b.z;o[7]=b.w;
}

// ---------------- generic fill ----------------
__global__ void fill_k(float* __restrict__ p, float v, int n){
  int i = blockIdx.x*blockDim.x + threadIdx.x;
  int stride = gridDim.x*blockDim.x;
  for (; i < n; i += stride) p[i] = v;
}

// ---------------- GEMM: C[M,128] = op(A)[M,128] @ W[128,128] (+bias)(+add) ----------------
// block: 256 thr, tile 128x128, micro-tile 8 rows x (4+4 split cols), K chunked by 32.
__global__ __launch_bounds__(256) void gemm128_k(
    const float* __restrict__ A, const float* __restrict__ W,
    const float* __restrict__ bias, const float* __restrict__ add,
    float* __restrict__ C, int geluIn)
{
  __shared__ float As[32*132];   // transposed [k][r], stride 132
  __shared__ float Ws[32*128];   // [k][c]
  const int tid = threadIdx.x;
  const int ty = tid >> 4, tx = tid & 15;
  const long row0 = (long)blockIdx.x * 128;
  const int r0 = ty*8, c0 = tx*4;
  float acc[8][8];
  #pragma unroll
  for (int i=0;i<8;i++)
    #pragma unroll
    for (int j=0;j<8;j++) acc[i][j] = 0.f;

  for (int kc=0;kc<4;kc++){
    // stage A (128 rows x 32 k) transposed into LDS
    #pragma unroll
    for (int i=0;i<2;i++){
      int g = tid + i*256;              // 0..511
      int r = g >> 2, k8 = g & 3;
      float a8[8];
      load8(A + (row0 + r)*DDIM + kc*32 + k8*8, a8);
      if (geluIn){
        #pragma unroll
        for (int j=0;j<8;j++) a8[j] = gelu_f(a8[j]);
      }
      #pragma unroll
      for (int j=0;j<8;j++) As[(k8*8+j)*132 + r] = a8[j];
    }
    // stage W (32 k x 128 c)
    #pragma unroll
    for (int i=0;i<2;i++){
      int g = tid + i*256;
      int k = g >> 4, c8 = g & 15;
      float w8[8];
      load8(W + (long)(kc*32 + k)*DDIM + c8*8, w8);
      *reinterpret_cast<float4*>(&Ws[k*DDIM + c8*8])   = make_float4(w8[0],w8[1],w8[2],w8[3]);
      *reinterpret_cast<float4*>(&Ws[k*DDIM + c8*8+4]) = make_float4(w8[4],w8[5],w8[6],w8[7]);
    }
    __syncthreads();
    #pragma unroll 8
    for (int k=0;k<32;k++){
      float4 alo = *reinterpret_cast<const float4*>(&As[k*132 + r0]);
      float4 ahi = *reinterpret_cast<const float4*>(&As[k*132 + r0 + 4]);
      float4 w0  = *reinterpret_cast<const float4*>(&Ws[k*DDIM + c0]);
      float4 w1  = *reinterpret_cast<const float4*>(&Ws[k*DDIM + c0 + 64]);
      float av[8] = {alo.x,alo.y,alo.z,alo.w,ahi.x,ahi.y,ahi.z,ahi.w};
      float wv[8] = {w0.x,w0.y,w0.z,w0.w,w1.x,w1.y,w1.z,w1.w};
      #pragma unroll
      for (int i=0;i<8;i++)
        #pragma unroll
        for (int j=0;j<8;j++) acc[i][j] += av[i]*wv[j];
    }
    __syncthreads();
  }
  float bv[8];
  #pragma unroll
  for (int j=0;j<4;j++){
    bv[j]   = bias ? bias[c0+j]    : 0.f;
    bv[4+j] = bias ? bias[c0+64+j] : 0.f;
  }
  #pragma unroll
  for (int i=0;i<8;i++){
    long r = row0 + r0 + i;
    float o[8];
    #pragma unroll
    for (int j=0;j<8;j++) o[j] = acc[i][j] + bv[j];
    if (add){
      float4 a0 = *reinterpret_cast<const float4*>(add + r*DDIM + c0);
      float4 a1 = *reinterpret_cast<const float4*>(add + r*DDIM + c0 + 64);
      o[0]+=a0.x; o[1]+=a0.y; o[2]+=a0.z; o[3]+=a0.w;
      o[4]+=a1.x; o[5]+=a1.y; o[6]+=a1.z; o[7]+=a1.w;
    }
    *reinterpret_cast<float4*>(C + r*DDIM + c0)      = make_float4(o[0],o[1],o[2],o[3]);
    *reinterpret_cast<float4*>(C + r*DDIM + c0 + 64) = make_float4(o[4],o[5],o[6],o[7]);
  }
}

// ---------------- GAT kernels (one edge type at a time) ----------------
__global__ void gat_scores_k(const float* __restrict__ h, const float* __restrict__ asrc,
                             const float* __restrict__ adst, float* __restrict__ ss,
                             float* __restrict__ ds, float* __restrict__ m)
{
  int n = blockIdx.x*256 + threadIdx.x;
  if (n >= NN) return;
  const float4* h4 = reinterpret_cast<const float4*>(h + (long)n*DDIM);
  float sv[4]={0,0,0,0}, dv[4]={0,0,0,0};
  #pragma unroll 8
  for (int l=0;l<32;l++){
    float4 hv = h4[l];
    int hd = l >> 3; int f = l*4;
    sv[hd] += hv.x*asrc[f] + hv.y*asrc[f+1] + hv.z*asrc[f+2] + hv.w*asrc[f+3];
    dv[hd] += hv.x*adst[f] + hv.y*adst[f+1] + hv.z*adst[f+2] + hv.w*adst[f+3];
  }
  #pragma unroll
  for (int hd=0;hd<4;hd++){
    ss[(long)n*4+hd] = sv[hd];
    ds[(long)n*4+hd] = dv[hd];
    m[(long)n*4+hd]  = lrelu(sv[hd]+dv[hd]);   // self-loop score seeds the max
  }
}

__global__ void gat_edge_a_k(const int* __restrict__ src, const int* __restrict__ dst,
                             const float* __restrict__ ss, const float* __restrict__ ds,
                             float* __restrict__ aB, float* __restrict__ m)
{
  int e = blockIdx.x*256 + threadIdx.x;
  if (e >= NEDGE) return;
  int s = src[e], d = dst[e];
  float4 sv = *reinterpret_cast<const float4*>(ss + (long)s*4);
  float4 dv = *reinterpret_cast<const float4*>(ds + (long)d*4);
  float4 a = make_float4(lrelu(sv.x+dv.x), lrelu(sv.y+dv.y), lrelu(sv.z+dv.z), lrelu(sv.w+dv.w));
  *reinterpret_cast<float4*>(aB + (long)e*4) = a;
  atomicMaxF(m + (long)d*4+0, a.x);
  atomicMaxF(m + (long)d*4+1, a.y);
  atomicMaxF(m + (long)d*4+2, a.z);
  atomicMaxF(m + (long)d*4+3, a.w);
}

__global__ void gat_sinit_k(const float* __restrict__ ss, const float* __restrict__ ds,
                            const float* __restrict__ m, float* __restrict__ sd)
{
  int n = blockIdx.x*256 + threadIdx.x;
  if (n >= NN) return;
  float4 sv = *reinterpret_cast<const float4*>(ss + (long)n*4);
  float4 dv = *reinterpret_cast<const float4*>(ds + (long)n*4);
  float4 mv = *reinterpret_cast<const float4*>(m + (long)n*4);
  float4 r = make_float4(__expf(lrelu(sv.x+dv.x)-mv.x), __expf(lrelu(sv.y+dv.y)-mv.y),
                         __expf(lrelu(sv.z+dv.z)-mv.z), __expf(lrelu(sv.w+dv.w)-mv.w));
  *reinterpret_cast<float4*>(sd + (long)n*4) = r;
}

__global__ void gat_edge_ex_k(const int* __restrict__ dst, float* __restrict__ aB,
                              const float* __restrict__ m, float* __restrict__ sd)
{
  int e = blockIdx.x*256 + threadIdx.x;
  if (e >= NEDGE) return;
  int d = dst[e];
  float4 a  = *reinterpret_cast<const float4*>(aB + (long)e*4);
  float4 mv = *reinterpret_cast<const float4*>(m + (long)d*4);
  float4 ex = make_float4(__expf(a.x-mv.x), __expf(a.y-mv.y), __expf(a.z-mv.z), __expf(a.w-mv.w));
  *reinterpret_cast<float4*>(aB + (long)e*4) = ex;
  atomicAdd(sd + (long)d*4+0, ex.x);
  atomicAdd(sd + (long)d*4+1, ex.y);
  atomicAdd(sd + (long)d*4+2, ex.z);
  atomicAdd(sd + (long)d*4+3, ex.w);
}

__global__ void gat_selfout_k(const float* __restrict__ ss, const float* __restrict__ ds,
                              const float* __restrict__ m, const float* __restrict__ sd,
                              const float* __restrict__ h, float* __restrict__ gout)
{
  int idx = blockIdx.x*256 + threadIdx.x;        // < NN*DDIM
  int n = idx >> 7, f = idx & 127, hd = f >> 5;
  float aself = lrelu(ss[(long)n*4+hd] + ds[(long)n*4+hd]);
  float alpha = __expf(aself - m[(long)n*4+hd]) / sd[(long)n*4+hd];
  gout[idx] += alpha * h[idx];
}

__global__ void gat_edge_out_k(const int* __restrict__ src, const int* __restrict__ dst,
                               const float* __restrict__ aB, const float* __restrict__ sd,
                               const float* __restrict__ h, float* __restrict__ gout)
{
  int e = blockIdx.x*8 + (threadIdx.x >> 5);
  if (e >= NEDGE) return;
  int l = threadIdx.x & 31;
  int s = src[e], d = dst[e];
  int hd = l >> 3;
  float alpha = aB[(long)e*4 + hd] / sd[(long)d*4 + hd];
  float4 hv = *reinterpret_cast<const float4*>(h + (long)s*DDIM + l*4);
  float* gp = gout + (long)d*DDIM + l*4;
  atomicAdd(gp+0, alpha*hv.x);
  atomicAdd(gp+1, alpha*hv.y);
  atomicAdd(gp+2, alpha*hv.z);
  atomicAdd(gp+3, alpha*hv.w);
}

// ---------------- residual + RMSNorm + LeakyReLU ----------------
__global__ void res_k(const float* __restrict__ xold, const float* __restrict__ xnew,
                      const float* __restrict__ norm, const float* __restrict__ gatb,
                      float* __restrict__ xout)
{
  int n = blockIdx.x*4 + (threadIdx.x >> 6);
  int l = threadIdx.x & 63;
  long base = (long)n*DDIM + l*2;
  float2 v = *reinterpret_cast<const float2*>(xnew + base);
  int f = l*2;
  if (gatb){
    v.x += gatb[f]   + gatb[DDIM+f]   + gatb[2*DDIM+f];
    v.y += gatb[f+1] + gatb[DDIM+f+1] + gatb[2*DDIM+f+1];
  }
  float sq = v.x*v.x + v.y*v.y;
  #pragma unroll
  for (int off=1; off<64; off<<=1) sq += __shfl_xor(sq, off, 64);
  float r = rsqrtf(sq*(1.f/DDIM) + EPSV);
  float x0 = xold[base], x1 = xold[base+1];
  float2 out;
  out.x = lrelu(x0 + norm[f]  *v.x*r);
  out.y = lrelu(x1 + norm[f+1]*v.y*r);
  *reinterpret_cast<float2*>(xout + base) = out;
}

__global__ void res3_k(const float* __restrict__ x2, const float* __restrict__ out2,
                       const float* __restrict__ skip, const float* __restrict__ norm,
                       float* __restrict__ xout)
{
  int n = blockIdx.x*4 + (threadIdx.x >> 6);
  int l = threadIdx.x & 63;
  long base = (long)n*DDIM + l*2;
  float g = 1.f/(1.f+__expf(-skip[0]));
  float2 o = *reinterpret_cast<const float2*>(out2 + base);
  float2 x = *reinterpret_cast<const float2*>(x2 + base);
  float2 v = make_float2(g*o.x + (1.f-g)*x.x, g*o.y + (1.f-g)*x.y);
  float sq = v.x*v.x + v.y*v.y;
  #pragma unroll
  for (int off=1; off<64; off<<=1) sq += __shfl_xor(sq, off, 64);
  float r = rsqrtf(sq*(1.f/DDIM) + EPSV);
  int f = l*2;
  float2 out;
  out.x = lrelu(x.x + norm[f]  *v.x*r);
  out.y = lrelu(x.y + norm[f+1]*v.y*r);
  *reinterpret_cast<float2*>(xout + base) = out;
}

// ---------------- HGT kernels ----------------
// fold rel into projection: Weff[t][c][h*32+e] = sum_d w[c][h*32+d]*rel[t][h][d][e]
__global__ void fold_k(const float* __restrict__ w, const float* __restrict__ b,
                       const float* __restrict__ rel, float* __restrict__ Weff,
                       float* __restrict__ beff)
{
  int idx = blockIdx.x*256 + threadIdx.x;
  if (idx >= NTYPE*DDIM*DDIM) return;
  int he = idx & 127, c = (idx >> 7) & 127, t = idx >> 14;
  int h = he >> 5, e = he & 31;
  const float* wrow = w + (long)c*DDIM + h*HDIM;
  const float* relm = rel + ((long)(t*NHEAD + h)*HDIM)*HDIM + e;
  float s = 0.f;
  #pragma unroll 8
  for (int d=0; d<HDIM; d++) s += wrow[d] * relm[d*HDIM];
  Weff[(long)t*DDIM*DDIM + (long)c*DDIM + he] = s;
  if (c == 0){
    float sb = 0.f;
    #pragma unroll 8
    for (int d=0; d<HDIM; d++) sb += b[h*HDIM+d] * relm[d*HDIM];
    beff[(long)t*DDIM + he] = sb;
  }
}

__global__ void hgt_score_k(const int* __restrict__ src, const int* __restrict__ dst,
                            const float* __restrict__ q, const float* __restrict__ kt,
                            const float* __restrict__ relp, float* __restrict__ S,
                            float* __restrict__ m)
{
  int e = blockIdx.x*8 + (threadIdx.x >> 5);
  if (e >= NEDGE) return;
  int l = threadIdx.x & 31;
  int s = src[e], d = dst[e];
  float4 qv = *reinterpret_cast<const float4*>(q  + (long)d*DDIM + l*4);
  float4 kv = *reinterpret_cast<const float4*>(kt + (long)s*DDIM + l*4);
  float p = qv.x*kv.x + qv.y*kv.y + qv.z*kv.z + qv.w*kv.w;
  p += __shfl_xor(p, 1, 64);
  p += __shfl_xor(p, 2, 64);
  p += __shfl_xor(p, 4, 64);
  if ((l & 7) == 0){
    int hd = l >> 3;
    float sc = p * relp[hd] * 0.17677669529663687f;   // 1/sqrt(32)
    S[(long)e*4 + hd] = sc;
    atomicMaxF(m + (long)d*4 + hd, sc);
  }
}

__global__ void hgt_ex_k(const int* __restrict__ ei, float* __restrict__ S,
                         const float* __restrict__ m, float* __restrict__ sd)
{
  int ge = blockIdx.x*256 + threadIdx.x;
  if (ge >= NTYPE*NEDGE) return;
  int t = ge >> 18, e = ge & (NEDGE-1);
  int d = ei[(long)t*2*NEDGE + NEDGE + e];
  float4 sc = *reinterpret_cast<const float4*>(S + (long)ge*4);
  float4 mv = *reinterpret_cast<const float4*>(m + (long)d*4);
  float4 ex = make_float4(__expf(sc.x-mv.x), __expf(sc.y-mv.y), __expf(sc.z-mv.z), __expf(sc.w-mv.w));
  *reinterpret_cast<float4*>(S + (long)ge*4) = ex;
  atomicAdd(sd + (long)d*4+0, ex.x);
  atomicAdd(sd + (long)d*4+1, ex.y);
  atomicAdd(sd + (long)d*4+2, ex.z);
  atomicAdd(sd + (long)d*4+3, ex.w);
}

__global__ void hgt_out_k(const int* __restrict__ src, const int* __restrict__ dst,
                          const float* __restrict__ S, const float* __restrict__ sd,
                          const float* __restrict__ vt, float* __restrict__ attn)
{
  int e = blockIdx.x*8 + (threadIdx.x >> 5);
  if (e >= NEDGE) return;
  int l = threadIdx.x & 31;
  int s = src[e], d = dst[e];
  int hd = l >> 3;
  float alpha = S[(long)e*4 + hd] / sd[(long)d*4 + hd];
  float4 vv = *reinterpret_cast<const float4*>(vt + (long)s*DDIM + l*4);
  float* ap = attn + (long)d*DDIM + l*4;
  atomicAdd(ap+0, alpha*vv.x);
  atomicAdd(ap+1, alpha*vv.y);
  atomicAdd(ap+2, alpha*vv.z);
  atomicAdd(ap+3, alpha*vv.w);
}

// ---------------- FiLM ----------------
__global__ void film1_k(const float* __restrict__ z, const float* __restrict__ w1,
                        const float* __restrict__ b1, float* __restrict__ f1)
{
  int idx = blockIdx.x*256 + threadIdx.x;
  if (idx >= NGRAPH*256) return;
  int j = idx & 255, b = idx >> 8;
  const float* zr = z + (long)b*DDIM;
  float s = b1[j];
  for (int k=0;k<DDIM;k++) s += zr[k] * w1[(long)k*256 + j];
  f1[idx] = gelu_f(s);
}

__global__ void film2_k(const float* __restrict__ f1, const float* __restrict__ w2,
                        const float* __restrict__ b2, float* __restrict__ gb)
{
  int idx = blockIdx.x*256 + threadIdx.x;
  if (idx >= NGRAPH*256) return;
  int j = idx & 255, b = idx >> 8;
  const float* fr = f1 + (long)b*256;
  float s = b2[j];
  for (int k=0;k<256;k++) s += fr[k] * w2[(long)k*256 + j];
  gb[idx] = s;
}

__global__ void final_k(const float* __restrict__ x3b, const float* __restrict__ gb,
                        float* __restrict__ out)
{
  int idx = blockIdx.x*256 + threadIdx.x;   // < NN*DDIM
  int f = idx & 127, n = idx >> 7, g = n >> 8;   // 256 nodes per graph
  float ga = 0.1f*tanhf(gb[(long)g*256 + f]);
  float be = 0.1f*tanhf(gb[(long)g*256 + 128 + f]);
  out[idx] = (1.f+ga)*x3b[idx] + be;
}

// ---------------- host ----------------
extern "C" void kernel_launch(void* const* d_in, const int* in_sizes, int n_in,
                              void* d_out, int out_size, void* d_ws, size_t ws_size,
                              hipStream_t stream)
{
  (void)in_sizes; (void)n_in; (void)out_size; (void)ws_size;
  const float* x_cell = (const float*)d_in[0];
  const float* x_emb  = (const float*)d_in[1];
  const float* z_h    = (const float*)d_in[2];
  const int*   ei     = (const int*)d_in[3];
  const float* gw[2]  = {(const float*)d_in[4],  (const float*)d_in[8]};
  const float* gas[2] = {(const float*)d_in[5],  (const float*)d_in[9]};
  const float* gad[2] = {(const float*)d_in[6],  (const float*)d_in[10]};
  const float* gbi[2] = {(const float*)d_in[7],  (const float*)d_in[11]};
  const float* norm1  = (const float*)d_in[12];
  const float* norm2  = (const float*)d_in[13];
  const float* norm3  = (const float*)d_in[14];
  const float* kw = (const float*)d_in[15]; const float* kb = (const float*)d_in[16];
  const float* qw = (const float*)d_in[17]; const float* qb = (const float*)d_in[18];
  const float* vw = (const float*)d_in[19]; const float* vb = (const float*)d_in[20];
  const float* relk = (const float*)d_in[21];
  const float* relv = (const float*)d_in[22];
  const float* relp = (const float*)d_in[23];
  const float* aw = (const float*)d_in[24]; const float* ab = (const float*)d_in[25];
  const float* skip = (const float*)d_in[26];
  const float* injw = (const float*)d_in[27]; const float* injb = (const float*)d_in[28];
  const float* fw1 = (const float*)d_in[29]; const float* fb1 = (const float*)d_in[30];
  const float* fw2 = (const float*)d_in[31]; const float* fb2 = (const float*)d_in[32];

  const long ND = (long)NN*DDIM;
  float* bufA = (float*)d_ws;                      // x1 / x2 / x3
  float* bufB = bufA + ND;                         // gat accum / q / attn / x3b
  float* bufC = bufB + ND;                         // h / kt / vt / out2
  float* Sbuf = bufC + ND;                         // per-edge scores (also GAT aBuf)
  float* ssb  = Sbuf + (long)NTYPE*NEDGE*4;
  float* dsb  = ssb + (long)NN*4;
  float* mb   = dsb + (long)NN*4;
  float* sdb  = mb  + (long)NN*4;
  float* WkE  = sdb + (long)NN*4;
  float* bkE  = WkE + (long)NTYPE*DDIM*DDIM;
  float* WvE  = bkE + (long)NTYPE*DDIM;
  float* bvE  = WvE + (long)NTYPE*DDIM*DDIM;
  float* f1b  = bvE + (long)NTYPE*DDIM;
  float* gbb  = f1b + (long)NGRAPH*256;

  const dim3 b256(256);

  // ---------- GAT layer 1 (input: x_cell) ----------
  fill_k<<<2048, b256, 0, stream>>>(bufB, 0.f, (int)ND);
  for (int t=0; t<NTYPE; t++){
    const int* srcp = ei + (long)t*2*NEDGE;
    const int* dstp = srcp + NEDGE;
    gemm128_k<<<NN/128, b256, 0, stream>>>(
        x_cell, gw[0] + (long)t*DDIM*DDIM, (const float*)nullptr, (const float*)nullptr, bufC, 0);
    gat_scores_k<<<NN/256, b256, 0, stream>>>(bufC, gas[0]+t*DDIM, gad[0]+t*DDIM, ssb, dsb, mb);
    gat_edge_a_k<<<NEDGE/256, b256, 0, stream>>>(srcp, dstp, ssb, dsb, Sbuf, mb);
    gat_sinit_k<<<NN/256, b256, 0, stream>>>(ssb, dsb, mb, sdb);
    gat_edge_ex_k<<<NEDGE/256, b256, 0, stream>>>(dstp, Sbuf, mb, sdb);
    gat_selfout_k<<<(NN*DDIM)/256, b256, 0, stream>>>(ssb, dsb, mb, sdb, bufC, bufB);
    gat_edge_out_k<<<NEDGE/8, b256, 0, stream>>>(srcp, dstp, Sbuf, sdb, bufC, bufB);
  }
  res_k<<<NN/4, b256, 0, stream>>>(x_cell, bufB, norm1, gbi[0], bufA);   // x1 -> A

  // ---------- GAT layer 2 (input: x1) ----------
  fill_k<<<2048, b256, 0, stream>>>(bufB, 0.f, (int)ND);
  for (int t=0; t<NTYPE; t++){
    const int* srcp = ei + (long)t*2*NEDGE;
    const int* dstp = srcp + NEDGE;
    gemm128_k<<<NN/128, b256, 0, stream>>>(
        bufA, gw[1] + (long)t*DDIM*DDIM, (const float*)nullptr, (const float*)nullptr, bufC, 0);
    gat_scores_k<<<NN/256, b256, 0, stream>>>(bufC, gas[1]+t*DDIM, gad[1]+t*DDIM, ssb, dsb, mb);
    gat_edge_a_k<<<NEDGE/256, b256, 0, stream>>>(srcp, dstp, ssb, dsb, Sbuf, mb);
    gat_sinit_k<<<NN/256, b256, 0, stream>>>(ssb, dsb, mb, sdb);
    gat_edge_ex_k<<<NEDGE/256, b256, 0, stream>>>(dstp, Sbuf, mb, sdb);
    gat_selfout_k<<<(NN*DDIM)/256, b256, 0, stream>>>(ssb, dsb, mb, sdb, bufC, bufB);
    gat_edge_out_k<<<NEDGE/8, b256, 0, stream>>>(srcp, dstp, Sbuf, sdb, bufC, bufB);
  }
  res_k<<<NN/4, b256, 0, stream>>>(bufA, bufB, norm2, gbi[1], bufA);     // x2 -> A

  // ---------- HGT ----------
  fold_k<<<(NTYPE*DDIM*DDIM)/256, b256, 0, stream>>>(kw, kb, relk, WkE, bkE);
  fold_k<<<(NTYPE*DDIM*DDIM)/256, b256, 0, stream>>>(vw, vb, relv, WvE, bvE);
  gemm128_k<<<NN/128, b256, 0, stream>>>(
      bufA, qw, qb, (const float*)nullptr, bufB, 0);                     // q -> B
  fill_k<<<512, b256, 0, stream>>>(mb, -INFINITY, NN*4);
  fill_k<<<512, b256, 0, stream>>>(sdb, 0.f, NN*4);
  for (int t=0; t<NTYPE; t++){
    const int* srcp = ei + (long)t*2*NEDGE;
    const int* dstp = srcp + NEDGE;
    gemm128_k<<<NN/128, b256, 0, stream>>>(
        bufA, WkE + (long)t*DDIM*DDIM, bkE + (long)t*DDIM, (const float*)nullptr, bufC, 0);
    hgt_score_k<<<NEDGE/8, b256, 0, stream>>>(srcp, dstp, bufB, bufC,
        relp + t*NHEAD, Sbuf + (long)t*NEDGE*4, mb);
  }
  hgt_ex_k<<<(NTYPE*NEDGE)/256, b256, 0, stream>>>(ei, Sbuf, mb, sdb);
  fill_k<<<2048, b256, 0, stream>>>(bufB, 0.f, (int)ND);                 // attn -> B (q dead)
  for (int t=0; t<NTYPE; t++){
    const int* srcp = ei + (long)t*2*NEDGE;
    const int* dstp = srcp + NEDGE;
    gemm128_k<<<NN/128, b256, 0, stream>>>(
        bufA, WvE + (long)t*DDIM*DDIM, bvE + (long)t*DDIM, (const float*)nullptr, bufC, 0);
    hgt_out_k<<<NEDGE/8, b256, 0, stream>>>(srcp, dstp, Sbuf + (long)t*NEDGE*4, sdb, bufC, bufB);
  }
  gemm128_k<<<NN/128, b256, 0, stream>>>(
      bufB, aw, ab, (const float*)nullptr, bufC, 1);                     // out2 = gelu(attn)@aw+ab -> C
  res3_k<<<NN/4, b256, 0, stream>>>(bufA, bufC, skip, norm3, bufA);      // x3 -> A

  // ---------- injection + FiLM ----------
  gemm128_k<<<NN/128, b256, 0, stream>>>(
      x_emb, injw, injb, bufA, bufB, 0);                                 // x3b -> B
  film1_k<<<(NGRAPH*256)/256, b256, 0, stream>>>(z_h, fw1, fb1, f1b);
  film2_k<<<(NGRAPH*256)/256, b256, 0, stream>>>(f1b, fw2, fb2, gbb);
  final_k<<<(NN*DDIM)/256, b256, 0, stream>>>(bufB, gbb, (float*)d_out);
}

// Round 3
// 1958.281 us; speedup vs baseline: 3.2970x; 3.2970x over previous
//
#include <hip/hip_runtime.h>
#include <math.h>
#include <cstdint>

// ---------------- problem constants ----------------
#define NN     131072     // nodes
#define DDIM   128        // hidden dim
#define NHEAD  4
#define HDIM   32
#define NTYPE  3
#define NEDGE  262144     // edges per type (2^18)
#define NGRAPH 512
#define EPSV   1e-6f
#define SLOPEV 0.2f

// ---------------- helpers ----------------
__device__ __forceinline__ float lrelu(float x){ return x >= 0.f ? x : SLOPEV*x; }
__device__ __forceinline__ float gelu_f(float x){ return 0.5f*x*(1.f+erff(x*0.70710678118654752f)); }
__device__ __forceinline__ void load8(const float* p, float* o){
  float4 a = *reinterpret_cast<const float4*>(p);
  float4 b = *reinterpret_cast<const float4*>(p+4);
  o[0]=a.x;o[1]=a.y;o[2]=a.z;o[3]=a.w;o[4]=b.x;o[5]=b.y;o[6]=b.z;o[7]=b.w;
}

// ---------------- generic fill ----------------
__global__ void fill_k(float* __restrict__ p, float v, int n){
  int i = blockIdx.x*blockDim.x + threadIdx.x;
  int stride = gridDim.x*blockDim.x;
  for (; i < n; i += stride) p[i] = v;
}

// ---------------- CSR build (dst-sorted, per edge type) ----------------
__global__ void hist_k(const int* __restrict__ ei, int* __restrict__ deg){
  int idx = blockIdx.x*256 + threadIdx.x;          // < 3E
  int t = idx >> 18, e = idx & (NEDGE-1);
  int d = ei[(long)t*2*NEDGE + NEDGE + e];
  atomicAdd(&deg[t*NN + d], 1);
}

__global__ void scan_a_k(const int* __restrict__ deg, int* __restrict__ rp,
                         int* __restrict__ csum){
  __shared__ int sh[256];
  int t = blockIdx.y, chunk = blockIdx.x, tid = threadIdx.x;
  const int* dp = deg + (long)t*NN + chunk*2048 + tid*8;
  int v[8]; int s = 0;
  #pragma unroll
  for (int i=0;i<8;i++){ v[i] = dp[i]; s += v[i]; }
  sh[tid] = s; __syncthreads();
  for (int off=1; off<256; off<<=1){
    int x = (tid>=off) ? sh[tid-off] : 0;
    __syncthreads();
    sh[tid] += x;
    __syncthreads();
  }
  int run = sh[tid] - s;                            // exclusive prefix
  int* op = rp + (long)t*(NN+1) + chunk*2048 + tid*8;
  #pragma unroll
  for (int i=0;i<8;i++){ op[i] = run; run += v[i]; }
  if (tid == 255) csum[t*64 + chunk] = sh[255];
}

__global__ void scan_b_k(int* __restrict__ csum){
  __shared__ int sh[64];
  int t = blockIdx.x, tid = threadIdx.x;
  int s = csum[t*64 + tid];
  sh[tid] = s; __syncthreads();
  for (int off=1; off<64; off<<=1){
    int x = (tid>=off) ? sh[tid-off] : 0;
    __syncthreads();
    sh[tid] += x;
    __syncthreads();
  }
  csum[t*64 + tid] = sh[tid] - s;                   // exclusive
}

__global__ void scan_c_k(int* __restrict__ rp, const int* __restrict__ csum){
  int t = blockIdx.y, chunk = blockIdx.x, tid = threadIdx.x;
  int add = csum[t*64 + chunk];
  int* op = rp + (long)t*(NN+1) + chunk*2048 + tid*8;
  #pragma unroll
  for (int i=0;i<8;i++) op[i] += add;
  if (chunk == 63 && tid == 255) rp[(long)t*(NN+1) + NN] = NEDGE;
}

__global__ void scatter_k(const int* __restrict__ ei, const int* __restrict__ rp,
                          int* __restrict__ cnt, int* __restrict__ srcs){
  int idx = blockIdx.x*256 + threadIdx.x;          // < 3E
  int t = idx >> 18, e = idx & (NEDGE-1);
  int s = ei[(long)t*2*NEDGE + e];
  int d = ei[(long)t*2*NEDGE + NEDGE + e];
  int pos = rp[(long)t*(NN+1) + d] + atomicAdd(&cnt[t*NN + d], 1);
  srcs[(long)t*NEDGE + pos] = s;
}

// ---------------- GEMM: C[M,128] = A[M,128] @ W[128,128] (+bias)(+add) ----------------
__global__ __launch_bounds__(256) void gemm128_k(
    const float* __restrict__ A, const float* __restrict__ W,
    const float* __restrict__ bias, const float* __restrict__ add,
    float* __restrict__ C)
{
  __shared__ float As[32*132];
  __shared__ float Ws[32*128];
  const int tid = threadIdx.x;
  const int ty = tid >> 4, tx = tid & 15;
  const long row0 = (long)blockIdx.x * 128;
  const int r0 = ty*8, c0 = tx*4;
  float acc[8][8];
  #pragma unroll
  for (int i=0;i<8;i++)
    #pragma unroll
    for (int j=0;j<8;j++) acc[i][j] = 0.f;

  for (int kc=0;kc<4;kc++){
    #pragma unroll
    for (int i=0;i<2;i++){
      int g = tid + i*256;
      int r = g >> 2, k8 = g & 3;
      float a8[8];
      load8(A + (row0 + r)*DDIM + kc*32 + k8*8, a8);
      #pragma unroll
      for (int j=0;j<8;j++) As[(k8*8+j)*132 + r] = a8[j];
    }
    #pragma unroll
    for (int i=0;i<2;i++){
      int g = tid + i*256;
      int k = g >> 4, c8 = g & 15;
      float w8[8];
      load8(W + (long)(kc*32 + k)*DDIM + c8*8, w8);
      *reinterpret_cast<float4*>(&Ws[k*DDIM + c8*8])   = make_float4(w8[0],w8[1],w8[2],w8[3]);
      *reinterpret_cast<float4*>(&Ws[k*DDIM + c8*8+4]) = make_float4(w8[4],w8[5],w8[6],w8[7]);
    }
    __syncthreads();
    #pragma unroll 8
    for (int k=0;k<32;k++){
      float4 alo = *reinterpret_cast<const float4*>(&As[k*132 + r0]);
      float4 ahi = *reinterpret_cast<const float4*>(&As[k*132 + r0 + 4]);
      float4 w0  = *reinterpret_cast<const float4*>(&Ws[k*DDIM + c0]);
      float4 w1  = *reinterpret_cast<const float4*>(&Ws[k*DDIM + c0 + 64]);
      float av[8] = {alo.x,alo.y,alo.z,alo.w,ahi.x,ahi.y,ahi.z,ahi.w};
      float wv[8] = {w0.x,w0.y,w0.z,w0.w,w1.x,w1.y,w1.z,w1.w};
      #pragma unroll
      for (int i=0;i<8;i++)
        #pragma unroll
        for (int j=0;j<8;j++) acc[i][j] += av[i]*wv[j];
    }
    __syncthreads();
  }
  float bv[8];
  #pragma unroll
  for (int j=0;j<4;j++){
    bv[j]   = bias ? bias[c0+j]    : 0.f;
    bv[4+j] = bias ? bias[c0+64+j] : 0.f;
  }
  #pragma unroll
  for (int i=0;i<8;i++){
    long r = row0 + r0 + i;
    float o[8];
    #pragma unroll
    for (int j=0;j<8;j++) o[j] = acc[i][j] + bv[j];
    if (add){
      float4 a0 = *reinterpret_cast<const float4*>(add + r*DDIM + c0);
      float4 a1 = *reinterpret_cast<const float4*>(add + r*DDIM + c0 + 64);
      o[0]+=a0.x; o[1]+=a0.y; o[2]+=a0.z; o[3]+=a0.w;
      o[4]+=a1.x; o[5]+=a1.y; o[6]+=a1.z; o[7]+=a1.w;
    }
    *reinterpret_cast<float4*>(C + r*DDIM + c0)      = make_float4(o[0],o[1],o[2],o[3]);
    *reinterpret_cast<float4*>(C + r*DDIM + c0 + 64) = make_float4(o[4],o[5],o[6],o[7]);
  }
}

// ---------------- GAT: per-node src/dst scores ----------------
__global__ void gat_scores_k(const float* __restrict__ h, const float* __restrict__ asrc,
                             const float* __restrict__ adst, float* __restrict__ ss,
                             float* __restrict__ ds)
{
  int n = blockIdx.x*256 + threadIdx.x;
  if (n >= NN) return;
  const float4* h4 = reinterpret_cast<const float4*>(h + (long)n*DDIM);
  float sv[4]={0,0,0,0}, dv[4]={0,0,0,0};
  #pragma unroll 8
  for (int l=0;l<32;l++){
    float4 hv = h4[l];
    int hd = l >> 3; int f = l*4;
    sv[hd] += hv.x*asrc[f] + hv.y*asrc[f+1] + hv.z*asrc[f+2] + hv.w*asrc[f+3];
    dv[hd] += hv.x*adst[f] + hv.y*adst[f+1] + hv.z*adst[f+2] + hv.w*adst[f+3];
  }
  #pragma unroll
  for (int hd=0;hd<4;hd++){
    ss[(long)n*4+hd] = sv[hd];
    ds[(long)n*4+hd] = dv[hd];
  }
}

// ---------------- GAT: fused online-softmax aggregation (per type) ----------------
__global__ __launch_bounds__(256) void gat_agg_k(
    const int* __restrict__ rp, const int* __restrict__ srcs,
    const float* __restrict__ h, const float* __restrict__ ss,
    const float* __restrict__ ds, float* __restrict__ acc, int addFlag)
{
  int node = blockIdx.x*8 + (threadIdx.x >> 5);
  int l = threadIdx.x & 31;
  int hd = l >> 3;
  int beg = rp[node], end = rp[node+1];
  float dsv = ds[(long)node*4 + hd];
  // self-loop seeds the online-softmax state
  float m = lrelu(ss[(long)node*4 + hd] + dsv);
  float lsum = 1.f;
  float4 a4 = *reinterpret_cast<const float4*>(h + (long)node*DDIM + l*4);
  for (int p=beg; p<end; p++){
    int s = srcs[p];
    float a = lrelu(ss[(long)s*4 + hd] + dsv);
    float4 hv = *reinterpret_cast<const float4*>(h + (long)s*DDIM + l*4);
    float mn = fmaxf(m, a);
    float wo = __expf(m - mn);
    float wn = __expf(a - mn);
    lsum = lsum*wo + wn;
    a4.x = a4.x*wo + wn*hv.x;
    a4.y = a4.y*wo + wn*hv.y;
    a4.z = a4.z*wo + wn*hv.z;
    a4.w = a4.w*wo + wn*hv.w;
    m = mn;
  }
  float inv = 1.f/lsum;
  float* op = acc + (long)node*DDIM + l*4;
  float4 o = make_float4(a4.x*inv, a4.y*inv, a4.z*inv, a4.w*inv);
  if (addFlag){
    float4 prev = *reinterpret_cast<const float4*>(op);
    o.x += prev.x; o.y += prev.y; o.z += prev.z; o.w += prev.w;
  }
  *reinterpret_cast<float4*>(op) = o;
}

// ---------------- residual + RMSNorm + LeakyReLU ----------------
__global__ void res_k(const float* __restrict__ xold, const float* __restrict__ xnew,
                      const float* __restrict__ norm, const float* __restrict__ gatb,
                      float* __restrict__ xout)
{
  int n = blockIdx.x*4 + (threadIdx.x >> 6);
  int l = threadIdx.x & 63;
  long base = (long)n*DDIM + l*2;
  float2 v = *reinterpret_cast<const float2*>(xnew + base);
  int f = l*2;
  if (gatb){
    v.x += gatb[f]   + gatb[DDIM+f]   + gatb[2*DDIM+f];
    v.y += gatb[f+1] + gatb[DDIM+f+1] + gatb[2*DDIM+f+1];
  }
  float sq = v.x*v.x + v.y*v.y;
  #pragma unroll
  for (int off=1; off<64; off<<=1) sq += __shfl_xor(sq, off, 64);
  float r = rsqrtf(sq*(1.f/DDIM) + EPSV);
  float x0 = xold[base], x1 = xold[base+1];
  float2 out;
  out.x = lrelu(x0 + norm[f]  *v.x*r);
  out.y = lrelu(x1 + norm[f+1]*v.y*r);
  *reinterpret_cast<float2*>(xout + base) = out;
}

__global__ void res3_k(const float* __restrict__ x2, const float* __restrict__ out2,
                       const float* __restrict__ skip, const float* __restrict__ norm,
                       float* __restrict__ xout)
{
  int n = blockIdx.x*4 + (threadIdx.x >> 6);
  int l = threadIdx.x & 63;
  long base = (long)n*DDIM + l*2;
  float g = 1.f/(1.f+__expf(-skip[0]));
  float2 o = *reinterpret_cast<const float2*>(out2 + base);
  float2 x = *reinterpret_cast<const float2*>(x2 + base);
  float2 v = make_float2(g*o.x + (1.f-g)*x.x, g*o.y + (1.f-g)*x.y);
  float sq = v.x*v.x + v.y*v.y;
  #pragma unroll
  for (int off=1; off<64; off<<=1) sq += __shfl_xor(sq, off, 64);
  float r = rsqrtf(sq*(1.f/DDIM) + EPSV);
  int f = l*2;
  float2 out;
  out.x = lrelu(x.x + norm[f]  *v.x*r);
  out.y = lrelu(x.y + norm[f+1]*v.y*r);
  *reinterpret_cast<float2*>(xout + base) = out;
}

// ---------------- HGT: fold rel into projection ----------------
__global__ void fold_k(const float* __restrict__ w, const float* __restrict__ b,
                       const float* __restrict__ rel, float* __restrict__ Weff,
                       float* __restrict__ beff)
{
  int idx = blockIdx.x*256 + threadIdx.x;
  if (idx >= NTYPE*DDIM*DDIM) return;
  int he = idx & 127, c = (idx >> 7) & 127, t = idx >> 14;
  int h = he >> 5, e = he & 31;
  const float* wrow = w + (long)c*DDIM + h*HDIM;
  const float* relm = rel + ((long)(t*NHEAD + h)*HDIM)*HDIM + e;
  float s = 0.f;
  #pragma unroll 8
  for (int d=0; d<HDIM; d++) s += wrow[d] * relm[d*HDIM];
  Weff[(long)t*DDIM*DDIM + (long)c*DDIM + he] = s;
  if (c == 0){
    float sb = 0.f;
    #pragma unroll 8
    for (int d=0; d<HDIM; d++) sb += b[h*HDIM+d] * relm[d*HDIM];
    beff[(long)t*DDIM + he] = sb;
  }
}

// ---------------- HGT phase A: scores + carried per-node max ----------------
__global__ __launch_bounds__(256) void hgt_score_pass_k(
    const int* __restrict__ rp, const int* __restrict__ srcs,
    const float* __restrict__ q, const float* __restrict__ kt,
    const float* __restrict__ relp, float* __restrict__ S,
    float* __restrict__ mbuf, int initFlag)
{
  int node = blockIdx.x*8 + (threadIdx.x >> 5);
  int l = threadIdx.x & 31;
  int hd = l >> 3, sub = l & 7;
  float4 qv = *reinterpret_cast<const float4*>(q + (long)node*DDIM + l*4);
  int beg = rp[node], end = rp[node+1];
  float m = initFlag ? -INFINITY : mbuf[(long)node*4 + hd];
  float scale = relp[hd] * 0.17677669529663687f;   // 1/sqrt(32)
  for (int p=beg; p<end; p++){
    int s = srcs[p];
    float4 kv = *reinterpret_cast<const float4*>(kt + (long)s*DDIM + l*4);
    float dot = qv.x*kv.x + qv.y*kv.y + qv.z*kv.z + qv.w*kv.w;
    dot += __shfl_xor(dot, 1, 64);
    dot += __shfl_xor(dot, 2, 64);
    dot += __shfl_xor(dot, 4, 64);
    float sc = dot * scale;
    if (sub == 0) S[(long)p*4 + hd] = sc;
    m = fmaxf(m, sc);
  }
  if (sub == 0) mbuf[(long)node*4 + hd] = m;
}

// ---------------- HGT phase B: exp-weighted accumulate + carried l ----------------
__global__ __launch_bounds__(256) void hgt_acc_pass_k(
    const int* __restrict__ rp, const int* __restrict__ srcs,
    const float* __restrict__ S, const float* __restrict__ vt,
    const float* __restrict__ mbuf, float* __restrict__ lbuf,
    float* __restrict__ acc, int initFlag)
{
  int node = blockIdx.x*8 + (threadIdx.x >> 5);
  int l = threadIdx.x & 31;
  int hd = l >> 3, sub = l & 7;
  int beg = rp[node], end = rp[node+1];
  float m = mbuf[(long)node*4 + hd];
  float lsum = initFlag ? 0.f : lbuf[(long)node*4 + hd];
  float* ap = acc + (long)node*DDIM + l*4;
  float4 a4;
  if (initFlag) a4 = make_float4(0.f,0.f,0.f,0.f);
  else          a4 = *reinterpret_cast<const float4*>(ap);
  for (int p=beg; p<end; p++){
    int s = srcs[p];
    float ex = __expf(S[(long)p*4 + hd] - m);
    float4 vv = *reinterpret_cast<const float4*>(vt + (long)s*DDIM + l*4);
    a4.x += ex*vv.x; a4.y += ex*vv.y; a4.z += ex*vv.z; a4.w += ex*vv.w;
    lsum += ex;
  }
  *reinterpret_cast<float4*>(ap) = a4;
  if (sub == 0) lbuf[(long)node*4 + hd] = lsum;
}

// ---------------- HGT finalize: gelu(acc / l) ----------------
__global__ void hgt_fin_k(const float* __restrict__ acc, const float* __restrict__ lbuf,
                          float* __restrict__ out)
{
  int idx = blockIdx.x*256 + threadIdx.x;        // < NN*DDIM
  int n = idx >> 7, f = idx & 127, hd = f >> 5;
  float ls = lbuf[(long)n*4 + hd];
  float v = (ls > 0.f) ? acc[idx]/ls : 0.f;
  out[idx] = gelu_f(v);
}

// ---------------- FiLM ----------------
__global__ void film1_k(const float* __restrict__ z, const float* __restrict__ w1,
                        const float* __restrict__ b1, float* __restrict__ f1)
{
  int idx = blockIdx.x*256 + threadIdx.x;
  if (idx >= NGRAPH*256) return;
  int j = idx & 255, b = idx >> 8;
  const float* zr = z + (long)b*DDIM;
  float s = b1[j];
  for (int k=0;k<DDIM;k++) s += zr[k] * w1[(long)k*256 + j];
  f1[idx] = gelu_f(s);
}

__global__ void film2_k(const float* __restrict__ f1, const float* __restrict__ w2,
                        const float* __restrict__ b2, float* __restrict__ gb)
{
  int idx = blockIdx.x*256 + threadIdx.x;
  if (idx >= NGRAPH*256) return;
  int j = idx & 255, b = idx >> 8;
  const float* fr = f1 + (long)b*256;
  float s = b2[j];
  for (int k=0;k<256;k++) s += fr[k] * w2[(long)k*256 + j];
  gb[idx] = s;
}

__global__ void final_k(const float* __restrict__ x3b, const float* __restrict__ gb,
                        float* __restrict__ out)
{
  int idx = blockIdx.x*256 + threadIdx.x;   // < NN*DDIM
  int f = idx & 127, n = idx >> 7, g = n >> 8;   // 256 nodes per graph
  float ga = 0.1f*tanhf(gb[(long)g*256 + f]);
  float be = 0.1f*tanhf(gb[(long)g*256 + 128 + f]);
  out[idx] = (1.f+ga)*x3b[idx] + be;
}

// ---------------- host ----------------
extern "C" void kernel_launch(void* const* d_in, const int* in_sizes, int n_in,
                              void* d_out, int out_size, void* d_ws, size_t ws_size,
                              hipStream_t stream)
{
  (void)in_sizes; (void)n_in; (void)out_size; (void)ws_size;
  const float* x_cell = (const float*)d_in[0];
  const float* x_emb  = (const float*)d_in[1];
  const float* z_h    = (const float*)d_in[2];
  const int*   ei     = (const int*)d_in[3];
  const float* gw[2]  = {(const float*)d_in[4],  (const float*)d_in[8]};
  const float* gas[2] = {(const float*)d_in[5],  (const float*)d_in[9]};
  const float* gad[2] = {(const float*)d_in[6],  (const float*)d_in[10]};
  const float* gbi[2] = {(const float*)d_in[7],  (const float*)d_in[11]};
  const float* norm1  = (const float*)d_in[12];
  const float* norm2  = (const float*)d_in[13];
  const float* norm3  = (const float*)d_in[14];
  const float* kw = (const float*)d_in[15]; const float* kb = (const float*)d_in[16];
  const float* qw = (const float*)d_in[17]; const float* qb = (const float*)d_in[18];
  const float* vw = (const float*)d_in[19]; const float* vb = (const float*)d_in[20];
  const float* relk = (const float*)d_in[21];
  const float* relv = (const float*)d_in[22];
  const float* relp = (const float*)d_in[23];
  const float* aw = (const float*)d_in[24]; const float* ab = (const float*)d_in[25];
  const float* skip = (const float*)d_in[26];
  const float* injw = (const float*)d_in[27]; const float* injb = (const float*)d_in[28];
  const float* fw1 = (const float*)d_in[29]; const float* fb1 = (const float*)d_in[30];
  const float* fw2 = (const float*)d_in[31]; const float* fb2 = (const float*)d_in[32];

  const long ND = (long)NN*DDIM;
  float* X    = (float*)d_ws;                    // x1 / x2 / x3
  float* P    = X + ND;                          // h_t / q / vt / gelu-in / x3b
  float* K    = P + ND;                          // gat acc / kt / hgt acc / out2
  float* Sbuf = K + ND;                          // per-edge HGT scores [3E,4]
  float* ssb  = Sbuf + (long)NTYPE*NEDGE*4;
  float* dsb  = ssb + (long)NN*4;
  float* mS   = dsb + (long)NN*4;                // HGT per-node max
  float* lS   = mS  + (long)NN*4;                // HGT per-node denom
  float* WkE  = lS  + (long)NN*4;
  float* bkE  = WkE + (long)NTYPE*DDIM*DDIM;
  float* WvE  = bkE + (long)NTYPE*DDIM;
  float* bvE  = WvE + (long)NTYPE*DDIM*DDIM;
  float* f1b  = bvE + (long)NTYPE*DDIM;
  float* gbb  = f1b + (long)NGRAPH*256;
  int*   deg  = (int*)(gbb + (long)NGRAPH*256);  // 3N (reused as cnt)
  int*   rp   = deg + (long)NTYPE*NN;            // 3(N+1)
  int*   srcs = rp  + (long)NTYPE*(NN+1);        // 3E
  int*   csum = srcs + (long)NTYPE*NEDGE;        // 192

  const dim3 b256(256);

  // ---------- CSR build (identical every launch) ----------
  fill_k<<<256, b256, 0, stream>>>((float*)deg, 0.f, NTYPE*NN);
  hist_k<<<(NTYPE*NEDGE)/256, b256, 0, stream>>>(ei, deg);
  scan_a_k<<<dim3(64, NTYPE), b256, 0, stream>>>(deg, rp, csum);
  scan_b_k<<<NTYPE, 64, 0, stream>>>(csum);
  scan_c_k<<<dim3(64, NTYPE), b256, 0, stream>>>(rp, csum);
  fill_k<<<256, b256, 0, stream>>>((float*)deg, 0.f, NTYPE*NN);   // cnt
  scatter_k<<<(NTYPE*NEDGE)/256, b256, 0, stream>>>(ei, rp, deg, srcs);

  // ---------- GAT layers ----------
  for (int layer=0; layer<2; layer++){
    const float* xin = (layer==0) ? x_cell : X;
    for (int t=0; t<NTYPE; t++){
      gemm128_k<<<NN/128, b256, 0, stream>>>(
          xin, gw[layer] + (long)t*DDIM*DDIM, (const float*)nullptr, (const float*)nullptr, P);
      gat_scores_k<<<NN/256, b256, 0, stream>>>(P, gas[layer]+t*DDIM, gad[layer]+t*DDIM, ssb, dsb);
      gat_agg_k<<<NN/8, b256, 0, stream>>>(rp + (long)t*(NN+1), srcs + (long)t*NEDGE,
                                           P, ssb, dsb, K, t>0);
    }
    res_k<<<NN/4, b256, 0, stream>>>(xin, K, (layer==0)?norm1:norm2, gbi[layer], X);
  }

  // ---------- HGT ----------
  fold_k<<<(NTYPE*DDIM*DDIM)/256, b256, 0, stream>>>(kw, kb, relk, WkE, bkE);
  fold_k<<<(NTYPE*DDIM*DDIM)/256, b256, 0, stream>>>(vw, vb, relv, WvE, bvE);
  gemm128_k<<<NN/128, b256, 0, stream>>>(X, qw, qb, (const float*)nullptr, P);   // q -> P
  for (int t=0; t<NTYPE; t++){
    gemm128_k<<<NN/128, b256, 0, stream>>>(
        X, WkE + (long)t*DDIM*DDIM, bkE + (long)t*DDIM, (const float*)nullptr, K);  // kt -> K
    hgt_score_pass_k<<<NN/8, b256, 0, stream>>>(rp + (long)t*(NN+1), srcs + (long)t*NEDGE,
        P, K, relp + t*NHEAD, Sbuf + (long)t*NEDGE*4, mS, t==0);
  }
  for (int t=0; t<NTYPE; t++){
    gemm128_k<<<NN/128, b256, 0, stream>>>(
        X, WvE + (long)t*DDIM*DDIM, bvE + (long)t*DDIM, (const float*)nullptr, P);  // vt -> P
    hgt_acc_pass_k<<<NN/8, b256, 0, stream>>>(rp + (long)t*(NN+1), srcs + (long)t*NEDGE,
        Sbuf + (long)t*NEDGE*4, P, mS, lS, K, t==0);
  }
  hgt_fin_k<<<(NN*DDIM)/256, b256, 0, stream>>>(K, lS, P);                       // gelu(acc/l) -> P
  gemm128_k<<<NN/128, b256, 0, stream>>>(P, aw, ab, (const float*)nullptr, K);   // out2 -> K
  res3_k<<<NN/4, b256, 0, stream>>>(X, K, skip, norm3, X);                       // x3 -> X

  // ---------- injection + FiLM ----------
  gemm128_k<<<NN/128, b256, 0, stream>>>(x_emb, injw, injb, X, P);               // x3b -> P
  film1_k<<<(NGRAPH*256)/256, b256, 0, stream>>>(z_h, fw1, fb1, f1b);
  film2_k<<<(NGRAPH*256)/256, b256, 0, stream>>>(f1b, fw2, fb2, gbb);
  final_k<<<(NN*DDIM)/256, b256, 0, stream>>>(P, gbb, (float*)d_out);
}

// Round 4
// 1348.333 us; speedup vs baseline: 4.7885x; 1.4524x over previous
//
#include <hip/hip_runtime.h>
#include <math.h>
#include <cstdint>

// ---------------- problem constants ----------------
#define NN     131072     // nodes
#define DDIM   128        // hidden dim
#define NHEAD  4
#define HDIM   32
#define NTYPE  3
#define NEDGE  262144     // edges per type (2^18)
#define NGRAPH 512
#define EPSV   1e-6f
#define SLOPEV 0.2f

typedef unsigned short bfraw;
typedef __attribute__((ext_vector_type(8))) short bf16x8;
typedef __attribute__((ext_vector_type(4))) float f32x4;

// ---------------- helpers ----------------
__device__ __forceinline__ float lrelu(float x){ return x >= 0.f ? x : SLOPEV*x; }
__device__ __forceinline__ float gelu_f(float x){ return 0.5f*x*(1.f+erff(x*0.70710678118654752f)); }
__device__ __forceinline__ bfraw f2bf(float f){
  unsigned int u = __float_as_uint(f);
  u += 0x7fffu + ((u >> 16) & 1u);          // RNE
  return (bfraw)(u >> 16);
}
__device__ __forceinline__ float4 ld_bf4(const bfraw* p){
  uint2 u = *reinterpret_cast<const uint2*>(p);
  float4 r;
  r.x = __uint_as_float(u.x << 16); r.y = __uint_as_float(u.x & 0xffff0000u);
  r.z = __uint_as_float(u.y << 16); r.w = __uint_as_float(u.y & 0xffff0000u);
  return r;
}
__device__ __forceinline__ void ld_bf8(const bfraw* p, float* o){
  uint4 v = *reinterpret_cast<const uint4*>(p);
  unsigned int w[4] = {v.x, v.y, v.z, v.w};
  #pragma unroll
  for (int i=0;i<4;i++){
    o[2*i]   = __uint_as_float(w[i] << 16);
    o[2*i+1] = __uint_as_float(w[i] & 0xffff0000u);
  }
}

// ---------------- generic fill / convert ----------------
__global__ void fill_k(float* __restrict__ p, float v, int n){
  int i = blockIdx.x*blockDim.x + threadIdx.x;
  int stride = gridDim.x*blockDim.x;
  for (; i < n; i += stride) p[i] = v;
}

__global__ void conv_k(const float* __restrict__ in, bfraw* __restrict__ out, int n){
  int i = blockIdx.x*blockDim.x + threadIdx.x;
  int stride = gridDim.x*blockDim.x;
  for (; i < n; i += stride) out[i] = f2bf(in[i]);
}

// ---------------- CSR build (dst-sorted, per edge type) ----------------
__global__ void hist_k(const int* __restrict__ ei, int* __restrict__ deg){
  int idx = blockIdx.x*256 + threadIdx.x;          // < 3E
  int t = idx >> 18, e = idx & (NEDGE-1);
  int d = ei[(long)t*2*NEDGE + NEDGE + e];
  atomicAdd(&deg[t*NN + d], 1);
}

__global__ void scan_a_k(const int* __restrict__ deg, int* __restrict__ rp,
                         int* __restrict__ csum){
  __shared__ int sh[256];
  int t = blockIdx.y, chunk = blockIdx.x, tid = threadIdx.x;
  const int* dp = deg + (long)t*NN + chunk*2048 + tid*8;
  int v[8]; int s = 0;
  #pragma unroll
  for (int i=0;i<8;i++){ v[i] = dp[i]; s += v[i]; }
  sh[tid] = s; __syncthreads();
  for (int off=1; off<256; off<<=1){
    int x = (tid>=off) ? sh[tid-off] : 0;
    __syncthreads();
    sh[tid] += x;
    __syncthreads();
  }
  int run = sh[tid] - s;                            // exclusive prefix
  int* op = rp + (long)t*(NN+1) + chunk*2048 + tid*8;
  #pragma unroll
  for (int i=0;i<8;i++){ op[i] = run; run += v[i]; }
  if (tid == 255) csum[t*64 + chunk] = sh[255];
}

__global__ void scan_b_k(int* __restrict__ csum){
  __shared__ int sh[64];
  int t = blockIdx.x, tid = threadIdx.x;
  int s = csum[t*64 + tid];
  sh[tid] = s; __syncthreads();
  for (int off=1; off<64; off<<=1){
    int x = (tid>=off) ? sh[tid-off] : 0;
    __syncthreads();
    sh[tid] += x;
    __syncthreads();
  }
  csum[t*64 + tid] = sh[tid] - s;                   // exclusive
}

__global__ void scan_c_k(int* __restrict__ rp, const int* __restrict__ csum){
  int t = blockIdx.y, chunk = blockIdx.x, tid = threadIdx.x;
  int add = csum[t*64 + chunk];
  int* op = rp + (long)t*(NN+1) + chunk*2048 + tid*8;
  #pragma unroll
  for (int i=0;i<8;i++) op[i] += add;
  if (chunk == 63 && tid == 255) rp[(long)t*(NN+1) + NN] = NEDGE;
}

__global__ void scatter_k(const int* __restrict__ ei, const int* __restrict__ rp,
                          int* __restrict__ cnt, int* __restrict__ srcs){
  int idx = blockIdx.x*256 + threadIdx.x;          // < 3E
  int t = idx >> 18, e = idx & (NEDGE-1);
  int s = ei[(long)t*2*NEDGE + e];
  int d = ei[(long)t*2*NEDGE + NEDGE + e];
  int pos = rp[(long)t*(NN+1) + d] + atomicAdd(&cnt[t*NN + d], 1);
  srcs[(long)t*NEDGE + pos] = s;
}

// ---------------- weight swizzle: f32 [128,128] -> bf16 b-frag layout ----------------
// Wsw[((nt*4+kc)*64+lane)*8+j] = W[kc*32+(lane>>4)*8+j][nt*16+(lane&15)]
__global__ void wswz_k(const float* g0a, const float* g0b, const float* g0c,
                       const float* g1a, const float* g1b, const float* g1c,
                       const float* qw,
                       const float* wk, const float* wv,   // [3][128][128] each
                       const float* aw, const float* injw,
                       bfraw* __restrict__ Wall)
{
  int y = blockIdx.y;
  const float* src;
  switch(y){
    case 0: src = g0a; break;  case 1: src = g0b; break;  case 2: src = g0c; break;
    case 3: src = g1a; break;  case 4: src = g1b; break;  case 5: src = g1c; break;
    case 6: src = qw; break;
    case 7: case 8: case 9: src = wk + (long)(y-7)*16384; break;
    case 10: case 11: case 12: src = wv + (long)(y-10)*16384; break;
    case 13: src = aw; break;
    default: src = injw; break;
  }
  int i = blockIdx.x*256 + threadIdx.x;            // < 16384
  int j = i & 7, lane = (i>>3) & 63, kc = (i>>9) & 3, nt = i >> 11;
  int k = kc*32 + ((lane>>4)<<3) + j;
  int n = nt*16 + (lane & 15);
  Wall[(long)y*16384 + i] = f2bf(src[k*DDIM + n]);
}

// ---------------- MFMA GEMM: C[M,128] = A[M,128]bf16 @ W[128,128]bf16 ----------------
// block 256 = 4 waves; block tile 128 rows; wave: 32 rows x 128 cols.
__global__ __launch_bounds__(256) void gemm_mfma_k(
    const bfraw* __restrict__ A, const bfraw* __restrict__ Wsw,
    const float* __restrict__ bias, const float* __restrict__ add,
    float* __restrict__ Cf, bfraw* __restrict__ Cb)
{
  __shared__ bfraw Wl[16384];
  const int tid = threadIdx.x;
  // stage swizzled W (32 KB)
  #pragma unroll
  for (int i=0;i<8;i++)
    *reinterpret_cast<uint4*>(Wl + (i*256+tid)*8) =
        *reinterpret_cast<const uint4*>(Wsw + (i*256+tid)*8);
  __syncthreads();

  const int w = tid >> 6, lane = tid & 63;
  const long blockRow = (long)blockIdx.x * 128;
  const long rowA = blockRow + w*32 + (lane & 15);
  const bfraw* A0 = A + rowA*DDIM + ((lane>>4)<<3);

  bf16x8 a0[4], a1[4];
  #pragma unroll
  for (int kc=0;kc<4;kc++){
    a0[kc] = *reinterpret_cast<const bf16x8*>(A0 + kc*32);
    a1[kc] = *reinterpret_cast<const bf16x8*>(A0 + 16*DDIM + kc*32);
  }
  f32x4 acc0[8], acc1[8];
  const f32x4 zz = {0.f,0.f,0.f,0.f};
  #pragma unroll
  for (int nt=0;nt<8;nt++){ acc0[nt]=zz; acc1[nt]=zz; }

  #pragma unroll
  for (int nt=0;nt<8;nt++){
    #pragma unroll
    for (int kc=0;kc<4;kc++){
      bf16x8 b = *reinterpret_cast<const bf16x8*>(Wl + ((nt*4+kc)*64 + lane)*8);
      acc0[nt] = __builtin_amdgcn_mfma_f32_16x16x32_bf16(a0[kc], b, acc0[nt], 0, 0, 0);
      acc1[nt] = __builtin_amdgcn_mfma_f32_16x16x32_bf16(a1[kc], b, acc1[nt], 0, 0, 0);
    }
  }

  const int q = lane >> 4;
  #pragma unroll
  for (int g=0; g<2; g++){
    #pragma unroll
    for (int nt=0;nt<8;nt++){
      int col = nt*16 + (lane & 15);
      float bv = bias ? bias[col] : 0.f;
      #pragma unroll
      for (int r=0;r<4;r++){
        long row = blockRow + w*32 + g*16 + q*4 + r;
        float v = (g ? acc1[nt][r] : acc0[nt][r]) + bv;
        if (add) v += add[row*DDIM + col];
        if (Cf) Cf[row*DDIM + col] = v;
        else    Cb[row*DDIM + col] = f2bf(v);
      }
    }
  }
}

// ---------------- GAT: per-node src/dst scores (h is bf16) ----------------
__global__ void gat_scores_k(const bfraw* __restrict__ h, const float* __restrict__ asrc,
                             const float* __restrict__ adst, float* __restrict__ ss,
                             float* __restrict__ ds)
{
  int n = blockIdx.x*256 + threadIdx.x;
  if (n >= NN) return;
  const bfraw* hp = h + (long)n*DDIM;
  float sv[4]={0,0,0,0}, dv[4]={0,0,0,0};
  #pragma unroll 4
  for (int l=0;l<16;l++){                         // 8 feats per iter
    float hv[8];
    ld_bf8(hp + l*8, hv);
    int hd = l >> 2; int f = l*8;
    #pragma unroll
    for (int j=0;j<8;j++){
      sv[hd] += hv[j]*asrc[f+j];
      dv[hd] += hv[j]*adst[f+j];
    }
  }
  #pragma unroll
  for (int hd=0;hd<4;hd++){
    ss[(long)n*4+hd] = sv[hd];
    ds[(long)n*4+hd] = dv[hd];
  }
}

// ---------------- GAT: fused online-softmax aggregation (per type) ----------------
__global__ __launch_bounds__(256) void gat_agg_k(
    const int* __restrict__ rp, const int* __restrict__ srcs,
    const bfraw* __restrict__ h, const float* __restrict__ ss,
    const float* __restrict__ ds, float* __restrict__ acc, int addFlag)
{
  int node = blockIdx.x*8 + (threadIdx.x >> 5);
  int l = threadIdx.x & 31;
  int hd = l >> 3;
  int beg = rp[node], end = rp[node+1];
  float dsv = ds[(long)node*4 + hd];
  float m = lrelu(ss[(long)node*4 + hd] + dsv);   // self-loop seeds state
  float lsum = 1.f;
  float4 a4 = ld_bf4(h + (long)node*DDIM + l*4);
  for (int p=beg; p<end; p++){
    int s = srcs[p];
    float a = lrelu(ss[(long)s*4 + hd] + dsv);
    float4 hv = ld_bf4(h + (long)s*DDIM + l*4);
    float mn = fmaxf(m, a);
    float wo = __expf(m - mn);
    float wn = __expf(a - mn);
    lsum = lsum*wo + wn;
    a4.x = a4.x*wo + wn*hv.x;
    a4.y = a4.y*wo + wn*hv.y;
    a4.z = a4.z*wo + wn*hv.z;
    a4.w = a4.w*wo + wn*hv.w;
    m = mn;
  }
  float inv = 1.f/lsum;
  float* op = acc + (long)node*DDIM + l*4;
  float4 o = make_float4(a4.x*inv, a4.y*inv, a4.z*inv, a4.w*inv);
  if (addFlag){
    float4 prev = *reinterpret_cast<const float4*>(op);
    o.x += prev.x; o.y += prev.y; o.z += prev.z; o.w += prev.w;
  }
  *reinterpret_cast<float4*>(op) = o;
}

// ---------------- residual + RMSNorm + LeakyReLU (writes f32 X + bf16 Xb) ----------------
__global__ void res_k(const float* __restrict__ xold, const float* __restrict__ xnew,
                      const float* __restrict__ norm, const float* __restrict__ gatb,
                      float* __restrict__ xout, bfraw* __restrict__ xb)
{
  int n = blockIdx.x*4 + (threadIdx.x >> 6);
  int l = threadIdx.x & 63;
  long base = (long)n*DDIM + l*2;
  float2 v = *reinterpret_cast<const float2*>(xnew + base);
  int f = l*2;
  if (gatb){
    v.x += gatb[f]   + gatb[DDIM+f]   + gatb[2*DDIM+f];
    v.y += gatb[f+1] + gatb[DDIM+f+1] + gatb[2*DDIM+f+1];
  }
  float sq = v.x*v.x + v.y*v.y;
  #pragma unroll
  for (int off=1; off<64; off<<=1) sq += __shfl_xor(sq, off, 64);
  float r = rsqrtf(sq*(1.f/DDIM) + EPSV);
  float x0 = xold[base], x1 = xold[base+1];
  float2 out;
  out.x = lrelu(x0 + norm[f]  *v.x*r);
  out.y = lrelu(x1 + norm[f+1]*v.y*r);
  *reinterpret_cast<float2*>(xout + base) = out;
  *reinterpret_cast<unsigned int*>(xb + base) =
      ((unsigned int)f2bf(out.y) << 16) | f2bf(out.x);
}

__global__ void res3_k(const float* __restrict__ x2, const float* __restrict__ out2,
                       const float* __restrict__ skip, const float* __restrict__ norm,
                       float* __restrict__ xout)
{
  int n = blockIdx.x*4 + (threadIdx.x >> 6);
  int l = threadIdx.x & 63;
  long base = (long)n*DDIM + l*2;
  float g = 1.f/(1.f+__expf(-skip[0]));
  float2 o = *reinterpret_cast<const float2*>(out2 + base);
  float2 x = *reinterpret_cast<const float2*>(x2 + base);
  float2 v = make_float2(g*o.x + (1.f-g)*x.x, g*o.y + (1.f-g)*x.y);
  float sq = v.x*v.x + v.y*v.y;
  #pragma unroll
  for (int off=1; off<64; off<<=1) sq += __shfl_xor(sq, off, 64);
  float r = rsqrtf(sq*(1.f/DDIM) + EPSV);
  int f = l*2;
  float2 out;
  out.x = lrelu(x.x + norm[f]  *v.x*r);
  out.y = lrelu(x.y + norm[f+1]*v.y*r);
  *reinterpret_cast<float2*>(xout + base) = out;
}

// ---------------- HGT: fold rel into projection ----------------
__global__ void fold_k(const float* __restrict__ w, const float* __restrict__ b,
                       const float* __restrict__ rel, float* __restrict__ Weff,
                       float* __restrict__ beff)
{
  int idx = blockIdx.x*256 + threadIdx.x;
  if (idx >= NTYPE*DDIM*DDIM) return;
  int he = idx & 127, c = (idx >> 7) & 127, t = idx >> 14;
  int h = he >> 5, e = he & 31;
  const float* wrow = w + (long)c*DDIM + h*HDIM;
  const float* relm = rel + ((long)(t*NHEAD + h)*HDIM)*HDIM + e;
  float s = 0.f;
  #pragma unroll 8
  for (int d=0; d<HDIM; d++) s += wrow[d] * relm[d*HDIM];
  Weff[(long)t*DDIM*DDIM + (long)c*DDIM + he] = s;
  if (c == 0){
    float sb = 0.f;
    #pragma unroll 8
    for (int d=0; d<HDIM; d++) sb += b[h*HDIM+d] * relm[d*HDIM];
    beff[(long)t*DDIM + he] = sb;
  }
}

// ---------------- HGT phase A: scores + carried per-node max ----------------
__global__ __launch_bounds__(256) void hgt_score_pass_k(
    const int* __restrict__ rp, const int* __restrict__ srcs,
    const float* __restrict__ q, const bfraw* __restrict__ kt,
    const float* __restrict__ relp, float* __restrict__ S,
    float* __restrict__ mbuf, int initFlag)
{
  int node = blockIdx.x*8 + (threadIdx.x >> 5);
  int l = threadIdx.x & 31;
  int hd = l >> 3, sub = l & 7;
  float4 qv = *reinterpret_cast<const float4*>(q + (long)node*DDIM + l*4);
  int beg = rp[node], end = rp[node+1];
  float m = initFlag ? -INFINITY : mbuf[(long)node*4 + hd];
  float scale = relp[hd] * 0.17677669529663687f;   // 1/sqrt(32)
  for (int p=beg; p<end; p++){
    int s = srcs[p];
    float4 kv = ld_bf4(kt + (long)s*DDIM + l*4);
    float dot = qv.x*kv.x + qv.y*kv.y + qv.z*kv.z + qv.w*kv.w;
    dot += __shfl_xor(dot, 1, 64);
    dot += __shfl_xor(dot, 2, 64);
    dot += __shfl_xor(dot, 4, 64);
    float sc = dot * scale;
    if (sub == 0) S[(long)p*4 + hd] = sc;
    m = fmaxf(m, sc);
  }
  if (sub == 0) mbuf[(long)node*4 + hd] = m;
}

// ---------------- HGT phase B: exp-weighted accumulate + carried l ----------------
__global__ __launch_bounds__(256) void hgt_acc_pass_k(
    const int* __restrict__ rp, const int* __restrict__ srcs,
    const float* __restrict__ S, const bfraw* __restrict__ vt,
    const float* __restrict__ mbuf, float* __restrict__ lbuf,
    float* __restrict__ acc, int initFlag)
{
  int node = blockIdx.x*8 + (threadIdx.x >> 5);
  int l = threadIdx.x & 31;
  int hd = l >> 3, sub = l & 7;
  int beg = rp[node], end = rp[node+1];
  float m = mbuf[(long)node*4 + hd];
  float lsum = initFlag ? 0.f : lbuf[(long)node*4 + hd];
  float* ap = acc + (long)node*DDIM + l*4;
  float4 a4;
  if (initFlag) a4 = make_float4(0.f,0.f,0.f,0.f);
  else          a4 = *reinterpret_cast<const float4*>(ap);
  for (int p=beg; p<end; p++){
    int s = srcs[p];
    float ex = __expf(S[(long)p*4 + hd] - m);
    float4 vv = ld_bf4(vt + (long)s*DDIM + l*4);
    a4.x += ex*vv.x; a4.y += ex*vv.y; a4.z += ex*vv.z; a4.w += ex*vv.w;
    lsum += ex;
  }
  *reinterpret_cast<float4*>(ap) = a4;
  if (sub == 0) lbuf[(long)node*4 + hd] = lsum;
}

// ---------------- HGT finalize: gelu(acc / l) -> bf16 ----------------
__global__ void hgt_fin_k(const float* __restrict__ acc, const float* __restrict__ lbuf,
                          bfraw* __restrict__ out)
{
  int idx = blockIdx.x*256 + threadIdx.x;        // < NN*DDIM
  int n = idx >> 7, f = idx & 127, hd = f >> 5;
  float ls = lbuf[(long)n*4 + hd];
  float v = (ls > 0.f) ? acc[idx]/ls : 0.f;
  out[idx] = f2bf(gelu_f(v));
}

// ---------------- FiLM ----------------
__global__ void film1_k(const float* __restrict__ z, const float* __restrict__ w1,
                        const float* __restrict__ b1, float* __restrict__ f1)
{
  int idx = blockIdx.x*256 + threadIdx.x;
  if (idx >= NGRAPH*256) return;
  int j = idx & 255, b = idx >> 8;
  const float* zr = z + (long)b*DDIM;
  float s = b1[j];
  for (int k=0;k<DDIM;k++) s += zr[k] * w1[(long)k*256 + j];
  f1[idx] = gelu_f(s);
}

__global__ void film2_k(const float* __restrict__ f1, const float* __restrict__ w2,
                        const float* __restrict__ b2, float* __restrict__ gb)
{
  int idx = blockIdx.x*256 + threadIdx.x;
  if (idx >= NGRAPH*256) return;
  int j = idx & 255, b = idx >> 8;
  const float* fr = f1 + (long)b*256;
  float s = b2[j];
  for (int k=0;k<256;k++) s += fr[k] * w2[(long)k*256 + j];
  gb[idx] = s;
}

__global__ void final_k(const float* __restrict__ x3b, const float* __restrict__ gb,
                        float* __restrict__ out)
{
  int idx = blockIdx.x*256 + threadIdx.x;   // < NN*DDIM
  int f = idx & 127, n = idx >> 7, g = n >> 8;   // 256 nodes per graph
  float ga = 0.1f*tanhf(gb[(long)g*256 + f]);
  float be = 0.1f*tanhf(gb[(long)g*256 + 128 + f]);
  out[idx] = (1.f+ga)*x3b[idx] + be;
}

// ---------------- host ----------------
extern "C" void kernel_launch(void* const* d_in, const int* in_sizes, int n_in,
                              void* d_out, int out_size, void* d_ws, size_t ws_size,
                              hipStream_t stream)
{
  (void)in_sizes; (void)n_in; (void)out_size; (void)ws_size;
  const float* x_cell = (const float*)d_in[0];
  const float* x_emb  = (const float*)d_in[1];
  const float* z_h    = (const float*)d_in[2];
  const int*   ei     = (const int*)d_in[3];
  const float* gw[2]  = {(const float*)d_in[4],  (const float*)d_in[8]};
  const float* gas[2] = {(const float*)d_in[5],  (const float*)d_in[9]};
  const float* gad[2] = {(const float*)d_in[6],  (const float*)d_in[10]};
  const float* gbi[2] = {(const float*)d_in[7],  (const float*)d_in[11]};
  const float* norm1  = (const float*)d_in[12];
  const float* norm2  = (const float*)d_in[13];
  const float* norm3  = (const float*)d_in[14];
  const float* kw = (const float*)d_in[15]; const float* kb = (const float*)d_in[16];
  const float* qw = (const float*)d_in[17]; const float* qb = (const float*)d_in[18];
  const float* vw = (const float*)d_in[19]; const float* vb = (const float*)d_in[20];
  const float* relk = (const float*)d_in[21];
  const float* relv = (const float*)d_in[22];
  const float* relp = (const float*)d_in[23];
  const float* aw = (const float*)d_in[24]; const float* ab = (const float*)d_in[25];
  const float* skip = (const float*)d_in[26];
  const float* injw = (const float*)d_in[27]; const float* injb = (const float*)d_in[28];
  const float* fw1 = (const float*)d_in[29]; const float* fb1 = (const float*)d_in[30];
  const float* fw2 = (const float*)d_in[31]; const float* fb2 = (const float*)d_in[32];

  const long ND = (long)NN*DDIM;
  float* X    = (float*)d_ws;                    // x1 / x2 / x3 (f32)
  float* K    = X + ND;                          // gat acc / q / hgt acc / out2 / x3b (f32)
  bfraw* Xb   = (bfraw*)(K + ND);                // bf16 GEMM A: x_cell/x1/x2, then x_emb
  bfraw* Hb   = Xb + ND;                         // bf16 GEMM out: h / kt / vt / gelu-attn
  float* Sbuf = (float*)(Hb + ND);               // HGT per-edge scores [3E,4]
  float* sA   = Sbuf + (long)NTYPE*NEDGE*4;      // GAT ss  | HGT m
  float* sB   = sA + (long)NN*4;                 // GAT ds  | HGT l
  float* WkE  = sB + (long)NN*4;
  float* bkE  = WkE + (long)NTYPE*DDIM*DDIM;
  float* WvE  = bkE + (long)NTYPE*DDIM;
  float* bvE  = WvE + (long)NTYPE*DDIM*DDIM;
  bfraw* Wall = (bfraw*)(bvE + (long)NTYPE*DDIM);   // 15 swizzled bf16 weights
  float* f1b  = (float*)(Wall + (long)15*16384);
  float* gbb  = f1b + (long)NGRAPH*256;
  int*   deg  = (int*)(gbb + (long)NGRAPH*256);  // 3N (reused as cnt)
  int*   rp   = deg + (long)NTYPE*NN;            // 3(N+1)
  int*   srcs = rp  + (long)NTYPE*(NN+1);        // 3E
  int*   csum = srcs + (long)NTYPE*NEDGE;        // 192

  const dim3 b256(256);
  float* NF = nullptr; bfraw* NB = nullptr;

  // ---------- CSR build ----------
  fill_k<<<256, b256, 0, stream>>>((float*)deg, 0.f, NTYPE*NN);
  hist_k<<<(NTYPE*NEDGE)/256, b256, 0, stream>>>(ei, deg);
  scan_a_k<<<dim3(64, NTYPE), b256, 0, stream>>>(deg, rp, csum);
  scan_b_k<<<NTYPE, 64, 0, stream>>>(csum);
  scan_c_k<<<dim3(64, NTYPE), b256, 0, stream>>>(rp, csum);
  fill_k<<<256, b256, 0, stream>>>((float*)deg, 0.f, NTYPE*NN);   // cnt
  scatter_k<<<(NTYPE*NEDGE)/256, b256, 0, stream>>>(ei, rp, deg, srcs);

  // ---------- weight prep ----------
  fold_k<<<(NTYPE*DDIM*DDIM)/256, b256, 0, stream>>>(kw, kb, relk, WkE, bkE);
  fold_k<<<(NTYPE*DDIM*DDIM)/256, b256, 0, stream>>>(vw, vb, relv, WvE, bvE);
  wswz_k<<<dim3(64, 15), b256, 0, stream>>>(
      gw[0], gw[0]+16384, gw[0]+32768,
      gw[1], gw[1]+16384, gw[1]+32768,
      qw, WkE, WvE, aw, injw, Wall);

  // ---------- GAT layers ----------
  conv_k<<<2048, b256, 0, stream>>>(x_cell, Xb, (int)ND);
  for (int layer=0; layer<2; layer++){
    for (int t=0; t<NTYPE; t++){
      gemm_mfma_k<<<NN/128, b256, 0, stream>>>(
          Xb, Wall + (long)(layer*3+t)*16384, NF, NF, NF, Hb);           // h -> Hb
      gat_scores_k<<<NN/256, b256, 0, stream>>>(Hb, gas[layer]+t*DDIM, gad[layer]+t*DDIM, sA, sB);
      gat_agg_k<<<NN/8, b256, 0, stream>>>(rp + (long)t*(NN+1), srcs + (long)t*NEDGE,
                                           Hb, sA, sB, K, t>0);
    }
    res_k<<<NN/4, b256, 0, stream>>>((layer==0)?x_cell:X, K,
                                     (layer==0)?norm1:norm2, gbi[layer], X, Xb);
  }

  // ---------- HGT ----------
  gemm_mfma_k<<<NN/128, b256, 0, stream>>>(Xb, Wall + (long)6*16384, qb, NF, K, NB);  // q -> K (f32)
  for (int t=0; t<NTYPE; t++){
    gemm_mfma_k<<<NN/128, b256, 0, stream>>>(
        Xb, Wall + (long)(7+t)*16384, bkE + t*DDIM, NF, NF, Hb);         // kt -> Hb
    hgt_score_pass_k<<<NN/8, b256, 0, stream>>>(rp + (long)t*(NN+1), srcs + (long)t*NEDGE,
        K, Hb, relp + t*NHEAD, Sbuf + (long)t*NEDGE*4, sA, t==0);
  }
  for (int t=0; t<NTYPE; t++){
    gemm_mfma_k<<<NN/128, b256, 0, stream>>>(
        Xb, Wall + (long)(10+t)*16384, bvE + t*DDIM, NF, NF, Hb);        // vt -> Hb
    hgt_acc_pass_k<<<NN/8, b256, 0, stream>>>(rp + (long)t*(NN+1), srcs + (long)t*NEDGE,
        Sbuf + (long)t*NEDGE*4, Hb, sA, sB, K, t==0);
  }
  conv_k<<<2048, b256, 0, stream>>>(x_emb, Xb, (int)ND);                 // Xb now x_emb
  hgt_fin_k<<<(NN*DDIM)/256, b256, 0, stream>>>(K, sB, Hb);              // gelu(acc/l) -> Hb
  gemm_mfma_k<<<NN/128, b256, 0, stream>>>(Hb, Wall + (long)13*16384, ab, NF, K, NB); // out2 -> K
  res3_k<<<NN/4, b256, 0, stream>>>(X, K, skip, norm3, X);               // x3 -> X
  gemm_mfma_k<<<NN/128, b256, 0, stream>>>(Xb, Wall + (long)14*16384, injb, X, K, NB); // x3b -> K

  // ---------- FiLM ----------
  film1_k<<<(NGRAPH*256)/256, b256, 0, stream>>>(z_h, fw1, fb1, f1b);
  film2_k<<<(NGRAPH*256)/256, b256, 0, stream>>>(f1b, fw2, fb2, gbb);
  final_k<<<(NN*DDIM)/256, b256, 0, stream>>>(K, gbb, (float*)d_out);
}